// Round 13
// baseline (306.293 us; speedup 1.0000x reference)
//
#include <hip/hip_runtime.h>
#include <hip/hip_cooperative_groups.h>
#include <math.h>

namespace cg = cooperative_groups;

#define M_DIM 1024
#define K_DIM 32
#define N_DIM 2048
#define ACC_ITERS 350      // Nesterov (strongly-convex momentum) iterations
#define POLISH_ITERS 50    // trailing plain-PGD polish
#define POW_ITERS 12       // power iterations for lambda_max

// ws layout (float offsets)
#define G_OFF 0            // 32*32 floats
#define T_OFF 2048         // 32*2048 floats

// v_readlane_b32: VALU, result in SGPR -> legal single-SGPR FMA operand.
__device__ __forceinline__ float bcast_lane(float x, int lane) {
    return __int_as_float(__builtin_amdgcn_readlane(__float_as_int(x), lane));
}

// ---------------------------------------------------------------------------
// Single cooperative kernel.
// Phase A: blocks 0..31  -> G row i  (G = theta_c^T theta_c)
//          blocks 32..95 -> T tile of 32 cols (full m-sum, no atomics)
//          blocks 96..511 idle
// grid.sync()
// Phase B: all 512 blocks -> round-10 PGD loop, 4 columns per block.
__global__ void __launch_bounds__(256, 2) kFused(const float* __restrict__ X,
                                                 const float* __restrict__ theta,
                                                 float* __restrict__ G,
                                                 float* __restrict__ T,
                                                 float* __restrict__ out) {
    __shared__ float lds[8192];     // 32 KB: phase-A reduce buf, phase-B Gsh
    int tid = threadIdx.x;
    int bid = blockIdx.x;

    // ---------------- Phase A ----------------
    if (bid < 32) {
        // ---- G row i ----
        int i = bid, j = tid & 31, ms = tid >> 5;
        float p = 0.f;
        for (int mq = 0; mq < 128; ++mq) {
            int m = ms * 128 + mq;
            float a = fmaxf(theta[m * K_DIM + i], 0.f);
            float b = fmaxf(theta[m * K_DIM + j], 0.f);
            p = fmaf(a, b, p);
        }
        lds[ms * 32 + j] = p;
        __syncthreads();
        if (ms == 0) {
            float s = p;
            for (int q = 1; q < 8; ++q) s += lds[q * 32 + j];
            G[i * 32 + j] = s;
        }
    } else if (bid < 96) {
        // ---- T tile: 32 columns, 8 m-slices across threads ----
        int tb = bid - 32;                     // 0..63
        int lc = tid & 31;
        int c  = tb * 32 + lc;
        int ms = tid >> 5;
        float acc[32];
#pragma unroll
        for (int q = 0; q < 32; ++q) acc[q] = 0.f;
        for (int mq = 0; mq < 128; ++mq) {
            int m = ms * 128 + mq;
            float x = X[m * N_DIM + c];
            const float4* t4 = reinterpret_cast<const float4*>(theta + m * K_DIM);
#pragma unroll
            for (int q = 0; q < 8; ++q) {
                float4 v = t4[q];
                acc[4 * q + 0] = fmaf(fmaxf(v.x, 0.f), x, acc[4 * q + 0]);
                acc[4 * q + 1] = fmaf(fmaxf(v.y, 0.f), x, acc[4 * q + 1]);
                acc[4 * q + 2] = fmaf(fmaxf(v.z, 0.f), x, acc[4 * q + 2]);
                acc[4 * q + 3] = fmaf(fmaxf(v.w, 0.f), x, acc[4 * q + 3]);
            }
        }
        // reduce 8 m-slices via LDS: [ms][i][lc]
#pragma unroll
        for (int q = 0; q < 32; ++q) lds[ms * 1024 + q * 32 + lc] = acc[q];
        __syncthreads();
        for (int q = 0; q < 4; ++q) {
            int e = q * 256 + tid;             // i = e>>5, cc = e&31
            float s = 0.f;
            for (int s8 = 0; s8 < 8; ++s8) s += lds[s8 * 1024 + e];
            T[(e >> 5) * N_DIM + tb * 32 + (e & 31)] = s;
        }
    }
    __threadfence();
    cg::this_grid().sync();

    // ---------------- Phase B: PGD (identical to round-10 kPGD) ----------
    // Gsh(r,c) = lds[r*33+c]; L at lds[1100], beta at lds[1101].
#pragma unroll
    for (int q = 0; q < 4; ++q) {
        int e = q * 256 + tid;
        lds[(e >> 5) * 33 + (e & 31)] = G[e];
    }
    __syncthreads();

    int i  = tid & 31;
    int wv = tid >> 6;
    int col = bid * 4 + wv;

    float g[32];
#pragma unroll
    for (int j = 0; j < 32; ++j) g[j] = lds[i * 33 + j];

    // --- wave 0: lambda_max + mu estimate ---
    if (tid < 64) {
        float v = 1.f, lam = 1.f;
        for (int p = 0; p < POW_ITERS; ++p) {
            float w = 0.f;
#pragma unroll
            for (int j = 0; j < 32; ++j) w = fmaf(g[j], bcast_lane(v, j), w);
            float n2 = w * w;
#pragma unroll
            for (int m = 1; m < 32; m <<= 1) n2 += __shfl_xor(n2, m, 32);
            lam = sqrtf(n2);
            v = w / lam;
        }
        float d = g[i];                         // diag entry -> trace
#pragma unroll
        for (int m = 1; m < 32; m <<= 1) d += __shfl_xor(d, m, 32);
        if (tid == 0) {
            float L  = lam + 1e-6f;
            float mu = 0.25f * (d - lam) * (1.0f / 31.0f);
            mu = fmaxf(mu, 1e-3f * L);
            float sL = sqrtf(L), sm = sqrtf(mu);
            lds[1100] = L;
            lds[1101] = (sL - sm) / (sL + sm);
        }
    }
    __syncthreads();

    float invL = 1.0f / lds[1100];
    float beta = lds[1101];

    float ar[32];
#pragma unroll
    for (int j = 0; j < 32; ++j) {
        ar[j] = ((j == i) ? 1.0f : 0.0f) - g[j] * invL;
        asm volatile("" : "+v"(ar[j]));
    }
    float t = T[i * N_DIM + col] * invL;

    // Full clobber of the Gsh region (destroys any LDS remat source).
    __syncthreads();
#pragma unroll
    for (int q = 0; q < 5; ++q) {
        int e = q * 256 + tid;
        if (e < 1102) lds[e] = 0.f;
    }
    __syncthreads();
    t = fmaf(lds[i * 33 + ((tid * 7) & 31)], 0.0f, t);  // non-foldable no-op

    // --- accelerated loop: w = max(A y + t, 0); y = w + beta (w - w_prev) ---
    float y = 0.f, bprev = 0.f;
    for (int it = 0; it < ACC_ITERS; ++it) {
        float bj[32];
#pragma unroll
        for (int j = 0; j < 32; ++j) bj[j] = bcast_lane(y, j);
        float a0 = t, a1 = 0.f, a2 = 0.f, a3 = 0.f;
#pragma unroll
        for (int j = 0; j < 32; j += 4) {
            a0 = fmaf(ar[j + 0], bj[j + 0], a0);
            a1 = fmaf(ar[j + 1], bj[j + 1], a1);
            a2 = fmaf(ar[j + 2], bj[j + 2], a2);
            a3 = fmaf(ar[j + 3], bj[j + 3], a3);
        }
        float w = fmaxf((a0 + a1) + (a2 + a3), 0.f);
        y = fmaf(beta, w - bprev, w);
        bprev = w;
    }
    // --- plain-PGD polish ---
    for (int it = 0; it < POLISH_ITERS; ++it) {
        float bj[32];
#pragma unroll
        for (int j = 0; j < 32; ++j) bj[j] = bcast_lane(y, j);
        float a0 = t, a1 = 0.f, a2 = 0.f, a3 = 0.f;
#pragma unroll
        for (int j = 0; j < 32; j += 4) {
            a0 = fmaf(ar[j + 0], bj[j + 0], a0);
            a1 = fmaf(ar[j + 1], bj[j + 1], a1);
            a2 = fmaf(ar[j + 2], bj[j + 2], a2);
            a3 = fmaf(ar[j + 3], bj[j + 3], a3);
        }
        y = fmaxf((a0 + a1) + (a2 + a3), 0.f);
    }

    if ((tid & 32) == 0) out[i * N_DIM + col] = y;
}

// ---------------------------------------------------------------------------
extern "C" void kernel_launch(void* const* d_in, const int* in_sizes, int n_in,
                              void* d_out, int out_size, void* d_ws, size_t ws_size,
                              hipStream_t stream) {
    const float* X     = (const float*)d_in[0];   // (1024, 2048) f32
    const float* theta = (const float*)d_in[1];   // (1024, 32) f32
    float* ws  = (float*)d_ws;
    float* G   = ws + G_OFF;
    float* T   = ws + T_OFF;
    float* out = (float*)d_out;

    void* args[] = {(void*)&X, (void*)&theta, (void*)&G, (void*)&T, (void*)&out};
    hipLaunchCooperativeKernel((const void*)kFused, dim3(512), dim3(256),
                               args, 0, stream);
}